// Round 3
// baseline (282.791 us; speedup 1.0000x reference)
//
#include <hip/hip_runtime.h>

// LSTM: B=16384 seqs, T=512, I=4, H=4, FC 4->1.
// 4 lanes/seq (unit j per lane); 1024 waves = 1 wave/SIMD.
// Round 3: kill the quarter-rate transcendentals. All gates via rational
// tanh (Eigen/XLA minimax, ~1e-6 max err): sigmoid(x)=0.5+0.5*tanh(x/2)
// with the 1/2 folded into W/b at load. Polys run as full-rate v_pk_fma.
// Each pair's two divisions share one v_rcp via 1/(d1*d2): 3 rcp/step total
// (was 5 exp2 + 5 rcp).

#define CH 8  // time-chunk for double-buffered X prefetch

typedef float v2f __attribute__((ext_vector_type(2)));

__device__ __forceinline__ v2f pk_fma(v2f a, v2f b, v2f c) {
    return __builtin_elementwise_fma(a, b, c);
}

// DPP quad_perm lane xor within aligned quads: xor1=0xB1, xor2=0x4E, xor3=0x1B
template <int CTRL>
__device__ __forceinline__ float quad_xor(float v) {
    int i = __float_as_int(v);
    int r = __builtin_amdgcn_mov_dpp(i, CTRL, 0xF, 0xF, true);
    return __int_as_float(r);
}

// Rational tanh (Eigen/XLA fp32 coefficients), 2-wide, Estrin.
// Emits numerator and denominator; caller batches the reciprocals.
__device__ __forceinline__ void tanh_nd(v2f x, v2f& num, v2f& den) {
    const float HI = 7.90531110763549805f;
    x = __builtin_elementwise_min(
            __builtin_elementwise_max(x, (v2f){-HI, -HI}), (v2f){HI, HI});
    v2f t  = x * x;          // x^2
    v2f t2 = t * t;          // x^4
    v2f t4 = t2 * t2;        // x^8
    const float a1 = 4.89352455891786e-03f,  a3  = 6.37261928875436e-04f,
                a5 = 1.48572235717979e-05f,  a7  = 5.12229709037114e-08f,
                a9 = -8.60467152213735e-11f, a11 = 2.00018790482477e-13f,
                a13 = -2.76076847742355e-16f;
    const float b0 = 4.89352518554385e-03f,  b2  = 2.26843463243900e-03f,
                b4 = 1.18534705686654e-04f,  b6  = 1.19825839466702e-06f;
    v2f p01 = pk_fma(t, (v2f){a3, a3},   (v2f){a1, a1});
    v2f p23 = pk_fma(t, (v2f){a7, a7},   (v2f){a5, a5});
    v2f p45 = pk_fma(t, (v2f){a11, a11}, (v2f){a9, a9});
    v2f q0  = pk_fma(t2, p23, p01);
    v2f q1  = pk_fma(t2, (v2f){a13, a13}, p45);
    v2f P   = pk_fma(t4, q1, q0);
    num = x * P;
    v2f d01 = pk_fma(t, (v2f){b2, b2}, (v2f){b0, b0});
    v2f d23 = pk_fma(t, (v2f){b6, b6}, (v2f){b4, b4});
    den = pk_fma(t2, d23, d01);
}

__device__ __forceinline__ float tanh_scalar(float x) {
    const float HI = 7.90531110763549805f;
    x = fminf(fmaxf(x, -HI), HI);
    float t  = x * x;
    float t2 = t * t;
    float t4 = t2 * t2;
    const float a1 = 4.89352455891786e-03f,  a3  = 6.37261928875436e-04f,
                a5 = 1.48572235717979e-05f,  a7  = 5.12229709037114e-08f,
                a9 = -8.60467152213735e-11f, a11 = 2.00018790482477e-13f,
                a13 = -2.76076847742355e-16f;
    const float b0 = 4.89352518554385e-03f,  b2  = 2.26843463243900e-03f,
                b4 = 1.18534705686654e-04f,  b6  = 1.19825839466702e-06f;
    float q0 = fmaf(t2, fmaf(t, a7, a5), fmaf(t, a3, a1));
    float q1 = fmaf(t2, a13, fmaf(t, a11, a9));
    float num = x * fmaf(t4, q1, q0);
    float den = fmaf(t2, fmaf(t, b6, b4), fmaf(t, b2, b0));
    return num * __builtin_amdgcn_rcpf(den);
}

__global__ __launch_bounds__(256) void lstm_h4_kernel(
    const float* __restrict__ X,
    const float* __restrict__ W_ih,
    const float* __restrict__ W_hh,
    const float* __restrict__ b_ih,
    const float* __restrict__ b_hh,
    const float* __restrict__ W_fc,
    const float* __restrict__ b_fc,
    float* __restrict__ out,
    int B, int T)
{
    int gid = blockIdx.x * blockDim.x + threadIdx.x;
    int b = gid >> 2;       // sequence index
    int j = gid & 3;        // hidden unit index
    if (b >= B) return;

    // Gate rows (PyTorch): 0-3=i, 4-7=f, 8-11=g, 12-15=o.
    // Pair 0 = (i_j, f_j); pair 1 = (g_j, o_j).
    // Sigmoid gates (i,f,o) get W,b pre-scaled by 0.5 (sigmoid-via-tanh).
    // whh_*[k] multiplies h from lane j^k -> column (j^k).
    v2f wih0[4], wih1[4], whh0[4], whh1[4], bias0, bias1;
    {
        const float sc[4] = {0.5f, 0.5f, 1.0f, 0.5f};   // i, f, g, o
        int rI = 0 * 4 + j, rF = 1 * 4 + j, rG = 2 * 4 + j, rO = 3 * 4 + j;
#pragma unroll
        for (int k = 0; k < 4; ++k) {
            wih0[k] = (v2f){sc[0] * W_ih[rI * 4 + k], sc[1] * W_ih[rF * 4 + k]};
            wih1[k] = (v2f){sc[2] * W_ih[rG * 4 + k], sc[3] * W_ih[rO * 4 + k]};
            int kc = j ^ k;
            whh0[k] = (v2f){sc[0] * W_hh[rI * 4 + kc], sc[1] * W_hh[rF * 4 + kc]};
            whh1[k] = (v2f){sc[2] * W_hh[rG * 4 + kc], sc[3] * W_hh[rO * 4 + kc]};
        }
        bias0 = (v2f){sc[0] * (b_ih[rI] + b_hh[rI]), sc[1] * (b_ih[rF] + b_hh[rF])};
        bias1 = (v2f){sc[2] * (b_ih[rG] + b_hh[rG]), sc[3] * (b_ih[rO] + b_hh[rO])};
    }

    const float4* __restrict__ xp = (const float4*)X + (size_t)b * T;

    float h = 0.0f, c = 0.0f;

    float4 cur[CH], nxt[CH];
#pragma unroll
    for (int i = 0; i < CH; ++i) cur[i] = xp[i];

    for (int tc = 0; tc < T; tc += CH) {
        if (tc + CH < T) {
#pragma unroll
            for (int i = 0; i < CH; ++i) nxt[i] = xp[tc + CH + i];
        }
#pragma unroll
        for (int i = 0; i < CH; ++i) {
            float4 x = cur[i];
            // ---- x path (independent of recurrence) ----
            v2f p0 = bias0, p1 = bias1;
            p0 = pk_fma(wih0[0], (v2f){x.x, x.x}, p0);
            p1 = pk_fma(wih1[0], (v2f){x.x, x.x}, p1);
            p0 = pk_fma(wih0[1], (v2f){x.y, x.y}, p0);
            p1 = pk_fma(wih1[1], (v2f){x.y, x.y}, p1);
            p0 = pk_fma(wih0[2], (v2f){x.z, x.z}, p0);
            p1 = pk_fma(wih1[2], (v2f){x.z, x.z}, p1);
            p0 = pk_fma(wih0[3], (v2f){x.w, x.w}, p0);
            p1 = pk_fma(wih1[3], (v2f){x.w, x.w}, p1);

            // ---- recurrence: tree the 4 h terms (depth 3, not 4) ----
            float h1 = quad_xor<0xB1>(h);
            float h2 = quad_xor<0x4E>(h);
            float h3 = quad_xor<0x1B>(h);
            v2f hb0 = (v2f){h,  h},  hb1 = (v2f){h1, h1};
            v2f hb2 = (v2f){h2, h2}, hb3 = (v2f){h3, h3};
            v2f u0a = pk_fma(whh0[0], hb0, p0);
            v2f u0b = pk_fma(whh0[2], hb2, whh0[3] * hb3);
            v2f u1a = pk_fma(whh1[0], hb0, p1);
            v2f u1b = pk_fma(whh1[2], hb2, whh1[3] * hb3);
            v2f u0 = pk_fma(whh0[1], hb1, u0a) + u0b;
            v2f u1 = pk_fma(whh1[1], hb1, u1a) + u1b;

            // ---- rational nonlinearities, batched reciprocals ----
            v2f n0, d0, n1, d1;
            tanh_nd(u0, n0, d0);   // (tanh(z_i/2), tanh(z_f/2))
            tanh_nd(u1, n1, d1);   // (tanh(z_g),   tanh(z_o/2))
            float s0 = d0.x * d0.y;
            float s1 = d1.x * d1.y;
            float q0r = __builtin_amdgcn_rcpf(s0);
            float q1r = __builtin_amdgcn_rcpf(s1);
            v2f t0 = n0 * ((v2f){q0r, q0r} * (v2f){d0.y, d0.x});
            v2f t1 = n1 * ((v2f){q1r, q1r} * (v2f){d1.y, d1.x});
            v2f IF = pk_fma(t0, (v2f){0.5f, 0.5f}, (v2f){0.5f, 0.5f});
            v2f GO = pk_fma(t1, (v2f){1.0f, 0.5f}, (v2f){0.0f, 0.5f});

            c = fmaf(IF.y, c, IF.x * GO.x);
            h = GO.y * tanh_scalar(c);
        }
#pragma unroll
        for (int i = 0; i < CH; ++i) cur[i] = nxt[i];
    }

    // out[b] = sum_j h_j * W_fc[j] + b_fc  (quad reduction)
    float partial = h * W_fc[j];
    partial += quad_xor<0xB1>(partial);
    partial += quad_xor<0x4E>(partial);
    if (j == 0) out[b] = partial + b_fc[0];
}

extern "C" void kernel_launch(void* const* d_in, const int* in_sizes, int n_in,
                              void* d_out, int out_size, void* d_ws, size_t ws_size,
                              hipStream_t stream) {
    const float* X    = (const float*)d_in[0];
    const float* W_ih = (const float*)d_in[1];
    const float* W_hh = (const float*)d_in[2];
    const float* b_ih = (const float*)d_in[3];
    const float* b_hh = (const float*)d_in[4];
    const float* W_fc = (const float*)d_in[5];
    const float* b_fc = (const float*)d_in[6];
    float* out = (float*)d_out;

    int B = out_size;                       // 16384
    int T = in_sizes[0] / (B * 4);          // 512 (I=4)

    int threads = B * 4;
    dim3 block(256);
    dim3 grid((threads + 255) / 256);
    lstm_h4_kernel<<<grid, block, 0, stream>>>(X, W_ih, W_hh, b_ih, b_hh,
                                               W_fc, b_fc, out, B, T);
}

// Round 4
// 266.437 us; speedup vs baseline: 1.0614x; 1.0614x over previous
//
#include <hip/hip_runtime.h>

// LSTM: B=16384 seqs, T=512, I=4, H=4, FC 4->1.
// Round 4: 8 lanes/seq -> 131072 threads = 2048 waves = 2 waves/SIMD (TLP to
// hide dep-chain + trans + DS latency; R1-R3 proved 1 wave/SIMD strands ~60%
// of cycles in stalls regardless of instruction mix).
// Lane s in [0,8): unit j=s&3, pair p=s>>2. p=0 computes (i_j,f_j) pre-acts
// as one v2f chain; p=1 computes (g_j,o_j). ds_swizzle xor-4 swaps pairs;
// both halves redundantly (bit-identically) update c_j,h_j, so each aligned
// quad holds h_0..h_3 and DPP quad_perm still broadcasts h for W_hh.
// Nonlinearities: exp2+rcp (R2 style — proven issue-minimal; R3's rational
// tanh was 1.7x more instructions for zero stall reduction).

#define CH 8  // time-chunk for double-buffered X prefetch

typedef float v2f __attribute__((ext_vector_type(2)));

__device__ __forceinline__ v2f pk_fma(v2f a, v2f b, v2f c) {
    return __builtin_elementwise_fma(a, b, c);
}

// DPP quad_perm lane xor within aligned quads: xor1=0xB1, xor2=0x4E, xor3=0x1B
template <int CTRL>
__device__ __forceinline__ float quad_xor(float v) {
    int i = __float_as_int(v);
    int r = __builtin_amdgcn_mov_dpp(i, CTRL, 0xF, 0xF, true);
    return __int_as_float(r);
}

// ds_swizzle BitMode xor-4: offset = (4<<10) | 0x1F = 0x101F
__device__ __forceinline__ float swz_xor4(float v) {
    int r = __builtin_amdgcn_ds_swizzle(__float_as_int(v), 0x101F);
    return __int_as_float(r);
}

__device__ __forceinline__ float fast_tanh(float x) {
    float e = __builtin_amdgcn_exp2f(-2.88539008f * x);   // exp(-2x)
    float r = __builtin_amdgcn_rcpf(1.0f + e);
    return fmaf(2.0f, r, -1.0f);
}

__global__ __launch_bounds__(256) void lstm_h4_kernel(
    const float* __restrict__ X,
    const float* __restrict__ W_ih,
    const float* __restrict__ W_hh,
    const float* __restrict__ b_ih,
    const float* __restrict__ b_hh,
    const float* __restrict__ W_fc,
    const float* __restrict__ b_fc,
    float* __restrict__ out,
    int B, int T)
{
    int gid = blockIdx.x * blockDim.x + threadIdx.x;
    int b = gid >> 3;        // sequence index
    int s = gid & 7;         // sub-lane within sequence
    int j = s & 3;           // hidden unit
    bool p1 = (s >> 2) != 0; // pair: 0 -> rows (i,f); 1 -> rows (g,o)
    if (b >= B) return;

    // Gate rows (PyTorch): 0-3=i, 4-7=f, 8-11=g, 12-15=o.
    int r0 = p1 ? (8 + j) : (0 + j);     // i or g row
    int r1 = p1 ? (12 + j) : (4 + j);    // f or o row
    v2f wih[4], whh[4], bias;
#pragma unroll
    for (int k = 0; k < 4; ++k) {
        wih[k] = (v2f){W_ih[r0 * 4 + k], W_ih[r1 * 4 + k]};
        int kc = j ^ k;                  // h from lane-quad xor k is h_{j^k}
        whh[k] = (v2f){W_hh[r0 * 4 + kc], W_hh[r1 * 4 + kc]};
    }
    bias = (v2f){b_ih[r0] + b_hh[r0], b_ih[r1] + b_hh[r1]};

    // Nonlinearity y = svec * rcp(1 + exp2(mvec*u)) + tvec, per component:
    //   sigmoid: m=-log2e,  s=1, t=0 ; tanh: m=-2log2e, s=2, t=-1
    const float L = 1.44269504f;
    const v2f mvec = p1 ? (v2f){-2.0f * L, -L} : (v2f){-L, -L};
    const v2f svec = p1 ? (v2f){2.0f, 1.0f}    : (v2f){1.0f, 1.0f};
    const v2f tvec = p1 ? (v2f){-1.0f, 0.0f}   : (v2f){0.0f, 0.0f};

    const float4* __restrict__ xp = (const float4*)X + (size_t)b * T;

    float h = 0.0f, c = 0.0f;

    float4 cur[CH], nxt[CH];
#pragma unroll
    for (int i = 0; i < CH; ++i) cur[i] = xp[i];

    for (int tc = 0; tc < T; tc += CH) {
        if (tc + CH < T) {
#pragma unroll
            for (int i = 0; i < CH; ++i) nxt[i] = xp[tc + CH + i];
        }
#pragma unroll
        for (int i = 0; i < CH; ++i) {
            float4 x = cur[i];
            // h broadcast within quad (all 8 lanes of a seq hold h_j)
            float h1 = quad_xor<0xB1>(h);
            float h2 = quad_xor<0x4E>(h);
            float h3 = quad_xor<0x1B>(h);
            // x path (independent of recurrence)
            v2f u = bias;
            u = pk_fma(wih[0], (v2f){x.x, x.x}, u);
            u = pk_fma(wih[1], (v2f){x.y, x.y}, u);
            u = pk_fma(wih[2], (v2f){x.z, x.z}, u);
            u = pk_fma(wih[3], (v2f){x.w, x.w}, u);
            // h path (tree, depth 3)
            v2f ta = pk_fma(whh[0], (v2f){h, h}, u);
            v2f tb = pk_fma(whh[2], (v2f){h2, h2}, whh[3] * (v2f){h3, h3});
            u = pk_fma(whh[1], (v2f){h1, h1}, ta) + tb;
            // own pair of gate values
            v2f a = u * mvec;
            v2f e = (v2f){__builtin_amdgcn_exp2f(a.x),
                          __builtin_amdgcn_exp2f(a.y)};
            v2f d = e + (v2f){1.0f, 1.0f};
            v2f r = (v2f){__builtin_amdgcn_rcpf(d.x),
                          __builtin_amdgcn_rcpf(d.y)};
            v2f own = pk_fma(svec, r, tvec);
            // exchange with partner (s ^ 4)
            v2f rcv = (v2f){swz_xor4(own.x), swz_xor4(own.y)};
            // own/rcv .x are (i,g) in some order, .y are (f,o)
            float fg = p1 ? rcv.y : own.y;
            float og = p1 ? own.y : rcv.y;
            float ig = own.x * rcv.x;        // i*g, commutative -> identical
            c = fmaf(fg, c, ig);
            h = og * fast_tanh(c);
        }
#pragma unroll
        for (int i = 0; i < CH; ++i) cur[i] = nxt[i];
    }

    // out[b] = sum_j h_j * W_fc[j] + b_fc  (quad reduction; write from s==0)
    float partial = h * W_fc[j];
    partial += quad_xor<0xB1>(partial);
    partial += quad_xor<0x4E>(partial);
    if (s == 0) out[b] = partial + b_fc[0];
}

extern "C" void kernel_launch(void* const* d_in, const int* in_sizes, int n_in,
                              void* d_out, int out_size, void* d_ws, size_t ws_size,
                              hipStream_t stream) {
    const float* X    = (const float*)d_in[0];
    const float* W_ih = (const float*)d_in[1];
    const float* W_hh = (const float*)d_in[2];
    const float* b_ih = (const float*)d_in[3];
    const float* b_hh = (const float*)d_in[4];
    const float* W_fc = (const float*)d_in[5];
    const float* b_fc = (const float*)d_in[6];
    float* out = (float*)d_out;

    int B = out_size;                       // 16384
    int T = in_sizes[0] / (B * 4);          // 512 (I=4)

    int threads = B * 8;
    dim3 block(256);
    dim3 grid((threads + 255) / 256);
    lstm_h4_kernel<<<grid, block, 0, stream>>>(X, W_ih, W_hh, b_ih, b_hh,
                                               W_fc, b_fc, out, B, T);
}